// Round 8
// baseline (421.052 us; speedup 1.0000x reference)
//
#include <hip/hip_runtime.h>
#include <hip/hip_fp16.h>

#define CAP 128   // max in-degree handled by the fast LDS path

__device__ __forceinline__ float sel4(float4 v, int h) {
  return h == 0 ? v.x : h == 1 ? v.y : h == 2 ? v.z : v.w;
}
__device__ __forceinline__ float sel8(const float a[8], int k) {
  float m0 = (k & 1) ? a[1] : a[0];
  float m1 = (k & 1) ? a[3] : a[2];
  float m2 = (k & 1) ? a[5] : a[4];
  float m3 = (k & 1) ? a[7] : a[6];
  float n0 = (k & 2) ? m1 : m0;
  float n1 = (k & 2) ? m3 : m2;
  return (k & 4) ? n1 : n0;
}

// ---------------- tiled GEMM + attention logits ----------------
template<int K, bool APPLY_BN>
__global__ void __launch_bounds__(256, 4)
gemm_tiled(const float* __restrict__ X, const float* __restrict__ W,
           const float* __restrict__ a_s, const float* __restrict__ a_d,
           const float* __restrict__ bnsum, const float* __restrict__ bnsq,
           const float* __restrict__ g, const float* __restrict__ be,
           __half* __restrict__ hp, float* __restrict__ al_s,
           float* __restrict__ al_d, int n)
{
  __shared__ float Wl[(K / 4) * 64 * 4];  // [(k4*64+lane)*4+c] = W[(k4*4+c)*64+lane]
  __shared__ float Xt[64 * K];            // row-major [64][K]

  for (int gi = threadIdx.x; gi < (K / 4) * 64; gi += 256) {
    int k4 = gi >> 6, ln = gi & 63;
    float4 w;
    w.x = W[(k4 * 4 + 0) * 64 + ln];
    w.y = W[(k4 * 4 + 1) * 64 + ln];
    w.z = W[(k4 * 4 + 2) * 64 + ln];
    w.w = W[(k4 * 4 + 3) * 64 + ln];
    *(float4*)&Wl[gi * 4] = w;
  }

  int row0 = blockIdx.x * 64;
  int nrows = min(64, n - row0);
  float4 sc, sh;
  if (APPLY_BN) {   // K==64 path: float4 col group fixed per thread
    int cg = (threadIdx.x & 15) * 4;
    float inv_n = 1.f / (float)n;
#pragma unroll
    for (int q = 0; q < 4; ++q) {
      float mu  = bnsum[cg + q] * inv_n;
      float var = bnsq[cg + q] * inv_n - mu * mu;
      float s   = g[cg + q] * rsqrtf(var + 1e-5f);
      ((float*)&sc)[q] = s;
      ((float*)&sh)[q] = be[cg + q] - mu * s;
    }
  }
  const float4* src = (const float4*)(X + (size_t)row0 * K);
  int nf4 = nrows * (K / 4);
  for (int i = threadIdx.x; i < nf4; i += 256) {
    float4 v = src[i];
    if (APPLY_BN) {
      v.x = fmaxf(v.x * sc.x + sh.x, 0.f);
      v.y = fmaxf(v.y * sc.y + sh.y, 0.f);
      v.z = fmaxf(v.z * sc.z + sh.z, 0.f);
      v.w = fmaxf(v.w * sc.w + sh.w, 0.f);
    }
    *(float4*)&Xt[i * 4] = v;
  }
  __syncthreads();

  int lane = threadIdx.x & 63;
  int wid  = threadIdx.x >> 6;
  int rbase = wid * 16;
  float acc[16];
#pragma unroll
  for (int r = 0; r < 16; ++r) acc[r] = 0.f;

  for (int k4 = 0; k4 < K / 4; ++k4) {
    float4 wv = *(const float4*)&Wl[(k4 * 64 + lane) * 4];
#pragma unroll
    for (int r = 0; r < 16; ++r) {
      float4 xv = *(const float4*)&Xt[(rbase + r) * K + k4 * 4];
      acc[r] += xv.x * wv.x + xv.y * wv.y + xv.z * wv.z + xv.w * wv.w;
    }
  }

  float as_l = a_s[lane], ad_l = a_d[lane];
  int h = lane >> 4, c = lane & 15;
#pragma unroll
  for (int r = 0; r < 16; ++r) {
    int lr = rbase + r;
    if (lr >= nrows) break;
    int row = row0 + lr;
    float a = acc[r];
    hp[(size_t)row * 64 + lane] = __float2half(a);
    float vs = a * as_l;
    float vd = a * ad_l;
#pragma unroll
    for (int off = 8; off >= 1; off >>= 1) {
      vs += __shfl_xor(vs, off, 64);
      vd += __shfl_xor(vd, off, 64);
    }
    if (c == 0) { al_s[row * 4 + h] = vs; al_d[row * 4 + h] = vd; }
  }
}

// ---------------- CSR build (once per call; reused by both layers) ----------------
__global__ void hist_k(const int* __restrict__ ei, int E, int N, int* __restrict__ count)
{
  int e = blockIdx.x * 256 + threadIdx.x;
  int Et = E + N;
  if (e >= Et) return;
  int d = (e < E) ? ei[E + e] : (e - E);
  atomicAdd(&count[d], 1);
}

__global__ void scan_block_k(const int* __restrict__ count, int* __restrict__ row_ptr,
                             int* __restrict__ partial, int n)
{
  __shared__ int woff[16];
  int tid = threadIdx.x;
  int i = blockIdx.x * 1024 + tid;
  int v = (i < n) ? count[i] : 0;
  int lane = tid & 63, wid = tid >> 6;
  int incl = v;
#pragma unroll
  for (int off = 1; off < 64; off <<= 1) {
    int t = __shfl_up(incl, off, 64);
    if (lane >= off) incl += t;
  }
  if (lane == 63) woff[wid] = incl;
  __syncthreads();
  if (tid < 16) {
    int wv = woff[tid];
    int winc = wv;
#pragma unroll
    for (int off = 1; off < 16; off <<= 1) {
      int t = __shfl_up(winc, off, 64);
      if (tid >= off) winc += t;
    }
    woff[tid] = winc - wv;
    if (tid == 15) partial[blockIdx.x] = winc;
  }
  __syncthreads();
  if (i < n) row_ptr[i] = woff[wid] + incl - v;
}

__global__ void scan_partial_k(int* __restrict__ partial, int* __restrict__ row_ptr,
                               int nb, int n)
{
  int tid = threadIdx.x;  // 64 threads
  int v = (tid < nb) ? partial[tid] : 0;
  int incl = v;
#pragma unroll
  for (int off = 1; off < 64; off <<= 1) {
    int t = __shfl_up(incl, off, 64);
    if (tid >= off) incl += t;
  }
  if (tid < nb) partial[tid] = incl - v;
  if (tid == 63) row_ptr[n] = incl;
}

__global__ void scan_add_k(int* __restrict__ row_ptr, int* __restrict__ cursor,
                           const int* __restrict__ partial, int n)
{
  int i = blockIdx.x * 1024 + threadIdx.x;
  if (i < n) {
    int r = row_ptr[i] + partial[blockIdx.x];
    row_ptr[i] = r;
    cursor[i] = r;
  }
}

__global__ void scatter_k(const int* __restrict__ ei, int E, int N,
                          int* __restrict__ cursor, int* __restrict__ col_src,
                          int* __restrict__ col_dst)
{
  int e = blockIdx.x * 256 + threadIdx.x;
  int Et = E + N;
  if (e >= Et) return;
  int s, d;
  if (e < E) { s = ei[e]; d = ei[E + e]; } else { s = d = e - E; }
  int pos = atomicAdd(&cursor[d], 1);
  col_src[pos] = s;
  col_dst[pos] = d;
}

// ---------------- edge-parallel softmax weights ----------------
__global__ void eweight_k(const int* __restrict__ csrc, const int* __restrict__ cdst,
                          const float* __restrict__ al_s, const float* __restrict__ al_d,
                          float4* __restrict__ ew, int Et)
{
  int e = blockIdx.x * 256 + threadIdx.x;
  if (e >= Et) return;
  int s = csrc[e], d = cdst[e];
  float4 a = *(const float4*)(al_s + (size_t)s * 4);
  float4 b = *(const float4*)(al_d + (size_t)d * 4);
  float ex = a.x + b.x; ex = ex >= 0.f ? ex : 0.2f * ex;
  float ey = a.y + b.y; ey = ey >= 0.f ? ey : 0.2f * ey;
  float ez = a.z + b.z; ez = ez >= 0.f ? ez : 0.2f * ez;
  float ewv = a.w + b.w; ewv = ewv >= 0.f ? ewv : 0.2f * ewv;
  ew[e] = make_float4(__expf(ex), __expf(ey), __expf(ez), __expf(ewv));
}

// ---------------- per-node aggregation (8 edges per memory instruction) ----------
// One wave per dst node. Stage: coalesced col_src + ew into LDS, zero-padded to
// a multiple of 8; per-head denominators via one masked shuffle reduce.
// Pass B: lane l handles 16-B chunk (l&7) of edge j+(l>>3)'s fp16 hp row —
// one global_load_dwordx4 fetches EIGHT 128-B rows (8x fewer gather requests,
// which is the measured bottleneck: ~55 cyc/request/CU service ceiling).
// Each lane accumulates its 8 channels (one head -> one weight/lane/edge);
// 3-step shfl_xor folds the 8 replicated groups; an intra-wave LDS bounce
// restores lane=channel for the output write + BN stats.
__global__ void __launch_bounds__(256)
node_agg(const int* __restrict__ row_ptr, const int* __restrict__ col_src,
         const float4* __restrict__ ew, const __half* __restrict__ hp,
         const float* __restrict__ bias, float* __restrict__ hpre,
         float* __restrict__ bnsum, float* __restrict__ bnsq, int n)
{
  __shared__ int   sh_s[4][CAP];
  __shared__ float sh_w[4][CAP * 4];
  __shared__ float sh_o[4][64];
  __shared__ float shs[64], shq[64];

  int lane = threadIdx.x & 63;
  int wid  = threadIdx.x >> 6;
  int grp  = lane >> 3;         // edge subgroup 0..7
  int q    = lane & 7;          // 16-B chunk within row (8 channels)
  int hq   = q >> 1;            // head of this lane's channel chunk
  float b  = bias[lane];
  float lsum = 0.f, lsq = 0.f;
  int nwaves = gridDim.x * 4;

  for (int d = blockIdx.x * 4 + wid; d < n; d += nwaves) {
    int beg = row_ptr[d], end = row_ptr[d + 1];
    int deg = end - beg;
    float outv;

    if (deg <= CAP) {
      int degR = (deg + 7) & ~7;
      float p0 = 0.f, p1 = 0.f, p2 = 0.f, p3 = 0.f;
      for (int jb = 0; jb < degR; jb += 64) {
        int jj = jb + lane;
        int s = 0;
        float4 w = make_float4(0.f, 0.f, 0.f, 0.f);
        if (jj < deg) {
          s = col_src[beg + jj];
          w = ew[beg + jj];
        }
        if (jj < degR) {
          sh_s[wid][jj] = s;
          *(float4*)&sh_w[wid][jj * 4] = w;
        }
        p0 += w.x; p1 += w.y; p2 += w.z; p3 += w.w;
      }
#pragma unroll
      for (int off = 32; off >= 1; off >>= 1) {
        p0 += __shfl_xor(p0, off, 64);
        p1 += __shfl_xor(p1, off, 64);
        p2 += __shfl_xor(p2, off, 64);
        p3 += __shfl_xor(p3, off, 64);
      }

      float acc[8];
#pragma unroll
      for (int k = 0; k < 8; ++k) acc[k] = 0.f;

      for (int j = 0; j < degR; j += 8) {
        int e = j + grp;
        int s = sh_s[wid][e];
        float wh = sh_w[wid][e * 4 + hq];
        uint4 raw = *(const uint4*)(hp + (size_t)s * 64 + q * 8);
        const __half2* hh = (const __half2*)&raw;
        float2 f0 = __half22float2(hh[0]);
        float2 f1 = __half22float2(hh[1]);
        float2 f2 = __half22float2(hh[2]);
        float2 f3 = __half22float2(hh[3]);
        acc[0] += wh * f0.x; acc[1] += wh * f0.y;
        acc[2] += wh * f1.x; acc[3] += wh * f1.y;
        acc[4] += wh * f2.x; acc[5] += wh * f2.y;
        acc[6] += wh * f3.x; acc[7] += wh * f3.y;
      }
      // fold the 8 replicated edge-subgroups
#pragma unroll
      for (int off = 8; off <= 32; off <<= 1) {
#pragma unroll
        for (int k = 0; k < 8; ++k) acc[k] += __shfl_xor(acc[k], off, 64);
      }
      // redistribute so lane = channel: lane writes channel (q*8 + grp)
      float v = sel8(acc, grp);
      sh_o[wid][q * 8 + grp] = v;
      __builtin_amdgcn_wave_barrier();
      float den = (lane < 16) ? p0 : (lane < 32) ? p1 : (lane < 48) ? p2 : p3;
      outv = sh_o[wid][lane] / (den + 1e-16f) + b;
    } else {
      // fallback: serial per node (deg > CAP; essentially never for this graph)
      int h = lane >> 4;
      float den = 0.f, acc = 0.f;
      for (int j = beg; j < end; ++j) {
        float wh = sel4(ew[j], h);
        den += wh;
        acc += wh * __half2float(hp[(size_t)col_src[j] * 64 + lane]);
      }
      outv = acc / (den + 1e-16f) + b;
    }

    hpre[(size_t)d * 64 + lane] = outv;
    lsum += outv; lsq += outv * outv;
  }

  if (threadIdx.x < 64) { shs[threadIdx.x] = 0.f; shq[threadIdx.x] = 0.f; }
  __syncthreads();
  atomicAdd(&shs[lane], lsum);
  atomicAdd(&shq[lane], lsq);
  __syncthreads();
  if (threadIdx.x < 64) {
    atomicAdd(&bnsum[threadIdx.x], shs[threadIdx.x]);
    atomicAdd(&bnsq[threadIdx.x],  shq[threadIdx.x]);
  }
}

// ---------------- BatchNorm apply (final layer, in-place on out) ----------------
__global__ void bn_apply(float* __restrict__ buf, const float* __restrict__ bnsum,
                         const float* __restrict__ bnsq, const float* __restrict__ g,
                         const float* __restrict__ be, int n)
{
  size_t i = (size_t)blockIdx.x * 256 + threadIdx.x;
  size_t total = (size_t)n * 64;
  if (i >= total) return;
  int c = (int)(i & 63);
  float inv_n = 1.f / (float)n;
  float mu  = bnsum[c] * inv_n;
  float var = bnsq[c] * inv_n - mu * mu;    // biased var, matches jnp .var()
  buf[i] = (buf[i] - mu) * rsqrtf(var + 1e-5f) * g[c] + be[c];
}

extern "C" void kernel_launch(void* const* d_in, const int* in_sizes, int n_in,
                              void* d_out, int out_size, void* d_ws, size_t ws_size,
                              hipStream_t stream) {
  const float* x   = (const float*)d_in[0];
  const int*   ei  = (const int*)d_in[1];
  const float* W0  = (const float*)d_in[2];
  const float* as0 = (const float*)d_in[3];
  const float* ad0 = (const float*)d_in[4];
  const float* b0  = (const float*)d_in[5];
  const float* g0  = (const float*)d_in[6];
  const float* be0 = (const float*)d_in[7];
  const float* W1  = (const float*)d_in[8];
  const float* as1 = (const float*)d_in[9];
  const float* ad1 = (const float*)d_in[10];
  const float* b1  = (const float*)d_in[11];
  const float* g1  = (const float*)d_in[12];
  const float* be1 = (const float*)d_in[13];
  float* out = (float*)d_out;

  int N = in_sizes[0] / 128;
  int E = in_sizes[1] / 2;
  int Et = E + N;

  char* w = (char*)d_ws;
  auto alloc = [&](size_t bytes) {
    char* p = w; w += (bytes + 255) & ~255ull; return p;
  };
  // count + bn stats contiguous -> single memset clears all of them
  int*    count = (int*)alloc((size_t)N * 4 + 4 * 64 * 4);
  float*  bnsum0 = (float*)(count + N);
  float*  bnsq0  = bnsum0 + 64;
  float*  bnsum1 = bnsq0 + 64;
  float*  bnsq1  = bnsum1 + 64;
  __half* hp    = (__half*)alloc((size_t)N * 64 * 2);   // fp16 hp (gathered matrix)
  float*  hpre0 = (float*)alloc((size_t)N * 64 * 4);    // layer-0 pre-BN output
  float*  als   = (float*)alloc((size_t)N * 4 * 4);
  float*  ald   = (float*)alloc((size_t)N * 4 * 4);
  int*    rowp  = (int*)alloc((size_t)(N + 1) * 4);
  int*    cursor= (int*)alloc((size_t)N * 4);
  int*    parts = (int*)alloc(64 * 4);
  int*    csrc  = (int*)alloc((size_t)Et * 4);
  int*    cdst  = (int*)alloc((size_t)Et * 4);
  float4* ew    = (float4*)alloc((size_t)Et * 16);

  dim3 blk(256);
  int gEt   = (Et + 255) / 256;
  int gN64  = (N * 64 + 255) / 256;
  int nb    = (N + 1023) / 1024;
  int gTile = (N + 63) / 64;

  hipMemsetAsync(count, 0, (size_t)N * 4 + 4 * 64 * 4, stream);

  // ---- CSR build (shared by both layers) ----
  hist_k<<<gEt, blk, 0, stream>>>(ei, E, N, count);
  scan_block_k<<<nb, 1024, 0, stream>>>(count, rowp, parts, N);
  scan_partial_k<<<1, 64, 0, stream>>>(parts, rowp, nb, N);
  scan_add_k<<<nb, 1024, 0, stream>>>(rowp, cursor, parts, N);
  scatter_k<<<gEt, blk, 0, stream>>>(ei, E, N, cursor, csrc, cdst);

  // ---- layer 0 ----
  gemm_tiled<128, false><<<gTile, blk, 0, stream>>>(x, W0, as0, ad0,
                                                    nullptr, nullptr, nullptr, nullptr,
                                                    hp, als, ald, N);
  eweight_k<<<gEt, blk, 0, stream>>>(csrc, cdst, als, ald, ew, Et);
  node_agg<<<4096, blk, 0, stream>>>(rowp, csrc, ew, hp, b0,
                                     hpre0, bnsum0, bnsq0, N);

  // ---- layer 1 (BN0 coeffs computed inline + ReLU fused into X staging) ----
  gemm_tiled<64, true><<<gTile, blk, 0, stream>>>(hpre0, W1, as1, ad1,
                                                  bnsum0, bnsq0, g0, be0,
                                                  hp, als, ald, N);
  eweight_k<<<gEt, blk, 0, stream>>>(csrc, cdst, als, ald, ew, Et);
  node_agg<<<4096, blk, 0, stream>>>(rowp, csrc, ew, hp, b1,
                                     out, bnsum1, bnsq1, N);
  bn_apply<<<gN64, blk, 0, stream>>>(out, bnsum1, bnsq1, g1, be1, N);
}